// Round 7
// baseline (268.217 us; speedup 1.0000x reference)
//
#include <hip/hip_runtime.h>

typedef _Float16 f16;
typedef _Float16 f16x2 __attribute__((ext_vector_type(2)));
typedef _Float16 f16x4 __attribute__((ext_vector_type(4)));
typedef _Float16 f16x8 __attribute__((ext_vector_type(8)));
typedef float f32x4 __attribute__((ext_vector_type(4)));
typedef int i32x4 __attribute__((ext_vector_type(4)));

#define MFMA(a, b, c) __builtin_amdgcn_mfma_f32_16x16x32_f16((a), (b), (c), 0, 0, 0)

typedef __attribute__((address_space(1))) const void gvoid;
typedef __attribute__((address_space(3))) void lvoid;

__device__ __forceinline__ void gload16(const void* g, void* l) {
    __builtin_amdgcn_global_load_lds((gvoid*)g, (lvoid*)l, 16, 0, 0);
}

// ---------------------------------------------------------------------------
// Kernel 1: cast f32 -> f16 for in_data (4M elems) and 4 weights (4x1M elems)
// ---------------------------------------------------------------------------
__global__ void cast_all(const float* __restrict__ x,
                         const float* __restrict__ w0, const float* __restrict__ w1,
                         const float* __restrict__ w2, const float* __restrict__ w3,
                         f16* __restrict__ xb, f16* __restrict__ wb) {
    const int NX = 4096 * 1024;
    int i = (blockIdx.x * 256 + threadIdx.x) * 4;
    if (i < NX) {
        float4 v = *(const float4*)(x + i);
        f16x4 o = {(f16)v.x, (f16)v.y, (f16)v.z, (f16)v.w};
        *(f16x4*)(xb + i) = o;
    } else {
        int j = i - NX;  // [0, 4M)
        const float* s = (j < (1 << 20)) ? w0 : (j < (2 << 20)) ? w1
                       : (j < (3 << 20)) ? w2 : w3;
        int loc = j & ((1 << 20) - 1);
        float4 v = *(const float4*)(s + loc);
        f16x4 o = {(f16)v.x, (f16)v.y, (f16)v.z, (f16)v.w};
        *(f16x4*)(wb + j) = o;
    }
}

// ---------------------------------------------------------------------------
// Kernel 2: QKV GEMM (unchanged control). C[m][n] = sum_k A[m][k]*B[n][k].
// M=4096, N=1024, K=1024, z=0 -> Q scaled by 0.125*log2(e), z=1 -> K,
// z=2 -> V written TRANSPOSED into VT[b*1024 + n][2048 s].
// ---------------------------------------------------------------------------
template <bool FINAL>
__global__ void gemm_bt(const f16* __restrict__ A, const f16* __restrict__ Bw,
                        f16* __restrict__ Cf, f16* __restrict__ VTo,
                        float* __restrict__ Co, const float* __restrict__ bias) {
    __shared__ __align__(16) f16 As[128 * 64];
    __shared__ __align__(16) f16 Bs[128 * 64];
    const int tid = threadIdx.x;
    const int lane = tid & 63, wid = tid >> 6;
    const int lo = lane & 15, hi = lane >> 4;
    const int wr = wid >> 1, wc = wid & 1;
    const int m0 = blockIdx.x * 128, n0 = blockIdx.y * 128;
    const char* Ab = (const char*)A;
    const char* Bb = (const char*)(Bw + (size_t)blockIdx.z * (1024 * 1024));

    f32x4 acc[4][4];
#pragma unroll
    for (int i = 0; i < 4; ++i)
#pragma unroll
        for (int j = 0; j < 4; ++j) acc[i][j] = (f32x4){0.f, 0.f, 0.f, 0.f};

    for (int kt = 0; kt < 16; ++kt) {
        const int kb = kt * 128;  // byte offset along K (64 f16)
#pragma unroll
        for (int rr = 0; rr < 4; ++rr) {
            int o = rr * 4096 + tid * 16;
            int row = o >> 7, colB = o & 127;
            gload16(Ab + (size_t)(m0 + row) * 2048 + kb + colB, (char*)As + o);
            gload16(Bb + (size_t)(n0 + row) * 2048 + kb + colB, (char*)Bs + o);
        }
        __syncthreads();
#pragma unroll
        for (int kc = 0; kc < 2; ++kc) {
            f16x8 af[4], bf[4];
#pragma unroll
            for (int f = 0; f < 4; ++f)
                af[f] = *(const f16x8*)(As + (wr * 64 + f * 16 + lo) * 64 + kc * 32 + hi * 8);
#pragma unroll
            for (int f = 0; f < 4; ++f)
                bf[f] = *(const f16x8*)(Bs + (wc * 64 + f * 16 + lo) * 64 + kc * 32 + hi * 8);
#pragma unroll
            for (int i = 0; i < 4; ++i)
#pragma unroll
                for (int j = 0; j < 4; ++j) acc[i][j] = MFMA(af[i], bf[j], acc[i][j]);
        }
        __syncthreads();
    }

    const int mbase = m0 + wr * 64 + hi * 4;
    const int nbase = n0 + wc * 64 + lo;
    if (FINAL) {
#pragma unroll
        for (int j = 0; j < 4; ++j) {
            float bj = bias[nbase + j * 16];
#pragma unroll
            for (int i = 0; i < 4; ++i)
#pragma unroll
                for (int r = 0; r < 4; ++r)
                    Co[(size_t)(mbase + i * 16 + r) * 1024 + nbase + j * 16] =
                        acc[i][j][r] + bj;
        }
    } else if (blockIdx.z == 2) {
        // V written transposed: VT[(b*1024 + n)][s],  m = b*2048+s
#pragma unroll
        for (int i = 0; i < 4; ++i)
#pragma unroll
            for (int j = 0; j < 4; ++j)
#pragma unroll
                for (int r = 0; r < 4; ++r) {
                    int m = mbase + i * 16 + r, n = nbase + j * 16;
                    VTo[(size_t)((m >> 11) * 1024 + n) * 2048 + (m & 2047)] =
                        (f16)acc[i][j][r];
                }
    } else {
        // z==0: fold 1/sqrt(64) * log2(e) into Q (softmax runs in exp2 domain)
        const float osc = (blockIdx.z == 0) ? 0.18033688f : 1.0f;
        f16* Cz = Cf + (size_t)blockIdx.z * (4096 * 1024);
#pragma unroll
        for (int i = 0; i < 4; ++i)
#pragma unroll
            for (int j = 0; j < 4; ++j)
#pragma unroll
                for (int r = 0; r < 4; ++r)
                    Cz[(size_t)(mbase + i * 16 + r) * 1024 + nbase + j * 16] =
                        (f16)(acc[i][j][r] * osc);
    }
}

// ---------------------------------------------------------------------------
// Kernel 3: causal flash attention — BARRIER-FREE, no LDS.
// K/V are L2-resident (512 KB per (b,h); 4 heads per XCD = 2 MB < 4 MB L2).
// Each wave loads its own K/V MFMA fragments global->VGPR (L1 shares the
// tile across the block's 4 waves). No __syncthreads anywhere.
//  - swapped QK^T: lane owns q=lo, kv=fj*16+hi*4+r
//  - exp2-domain softmax, defer-max (thr=8), per-lane partial row-sum
//  - P redistributed to PV B-fragments in registers (16 shfl + 8 selects)
//  - PV = MFMA(V_frag, P_frag) -> ctx^T; corr & 1/l lane-local
// Grid (32 bh, 32 qt reversed) -> XCD = bh%8. 4 waves x 16 q-rows, KVBLK=64.
// ---------------------------------------------------------------------------
__global__ __launch_bounds__(256) void attn(const f16* __restrict__ Q,
                                            const f16* __restrict__ K,
                                            const f16* __restrict__ VT,
                                            f16* __restrict__ CTX) {
    const int tid = threadIdx.x;
    const int lane = tid & 63, w = tid >> 6;
    const int lo = lane & 15, hi = lane >> 4;
    const int bh = blockIdx.x;
    const int qt = 31 - blockIdx.y;  // heavy tiles dispatch first
    const int b = bh >> 4, h = bh & 15;
    const int qw0 = qt * 64 + w * 16;
    const int qglob = qw0 + lo;

    // Q fragments (B-operand of swapped QK^T): col=q=lo, k=kc*32+hi*8+j
    const f16* qrow = Q + (size_t)(b * 2048 + qw0 + lo) * 1024 + h * 64 + hi * 8;
    const f16x8 qa0 = *(const f16x8*)(qrow);
    const f16x8 qa1 = *(const f16x8*)(qrow + 32);

    // ctx^T: lane owns d = df*16 + hi*4 + r, q = qw0 + lo
    f32x4 ctx[4];
#pragma unroll
    for (int d = 0; d < 4; ++d) ctx[d] = (f32x4){0.f, 0.f, 0.f, 0.f};
    float mrun = -3e38f, lsum = 0.f;

    // shfl indices for the P redistribution (dest (hi,j2) <- src hi-group)
    const int idx0 = (2 * (hi & 1)) * 16 + lo;   // j2 in {0,1}
    const int idx1 = idx0 + 16;                  // j2 in {2,3}

    // Per-fj K row pointers (row = kv0 + fj*16 + lo), advance 64 rows/step.
    // Per-df V^T row pointers (row = h*64 + df*16 + lo), advance 64 cols/step.
    const f16* kp[4];
    const f16* vp[4];
#pragma unroll
    for (int fj = 0; fj < 4; ++fj)
        kp[fj] = K + (size_t)(b * 2048 + fj * 16 + lo) * 1024 + h * 64 + hi * 8;
#pragma unroll
    for (int df = 0; df < 4; ++df)
        vp[df] = VT + (size_t)(b * 1024 + h * 64 + df * 16 + lo) * 2048 + hi * 8;

    for (int t = 0; t <= qt; ++t) {
        // ---- load K fragments (16B each, L1/L2-hot) ----
        f16x8 kf[4][2];
#pragma unroll
        for (int fj = 0; fj < 4; ++fj) {
            kf[fj][0] = *(const f16x8*)(kp[fj]);
            kf[fj][1] = *(const f16x8*)(kp[fj] + 32);
        }
        // ---- QK^T swapped: lane owns q=lo, kv = fj*16 + hi*4 + r ----
        f32x4 s4[4];
        __builtin_amdgcn_s_setprio(1);
#pragma unroll
        for (int fj = 0; fj < 4; ++fj) {
            f32x4 a = (f32x4){0.f, 0.f, 0.f, 0.f};
            a = MFMA(kf[fj][0], qa0, a);
            a = MFMA(kf[fj][1], qa1, a);
            s4[fj] = a;
        }
        __builtin_amdgcn_s_setprio(0);

        // ---- issue V fragment loads now; latency hides under softmax ----
        f16x8 vf[4][2];
#pragma unroll
        for (int df = 0; df < 4; ++df) {
            vf[df][0] = *(const f16x8*)(vp[df]);
            vf[df][1] = *(const f16x8*)(vp[df] + 32);
        }

        // ---- softmax (exp2 domain), defer-max ----
        float pv[16];
        if (t == qt) {  // only the diagonal tile masks (wave-uniform branch)
#pragma unroll
            for (int fj = 0; fj < 4; ++fj)
#pragma unroll
                for (int r = 0; r < 4; ++r) {
                    const int kvg = t * 64 + fj * 16 + hi * 4 + r;
                    pv[fj * 4 + r] = (kvg > qglob) ? -1e38f : s4[fj][r];
                }
        } else {
#pragma unroll
            for (int fj = 0; fj < 4; ++fj)
#pragma unroll
                for (int r = 0; r < 4; ++r) pv[fj * 4 + r] = s4[fj][r];
        }

        // lane-local max of 16 (tree)
        float tm[8];
#pragma unroll
        for (int i = 0; i < 8; ++i) tm[i] = fmaxf(pv[i], pv[i + 8]);
#pragma unroll
        for (int i = 0; i < 4; ++i) tm[i] = fmaxf(tm[i], tm[i + 4]);
        const float mxl = fmaxf(fmaxf(tm[0], tm[1]), fmaxf(tm[2], tm[3]));

        if (__any(mxl > mrun + 8.0f)) {  // rescale path (rare after warmup)
            float mxg = fmaxf(mxl, __shfl_xor(mxl, 16));
            mxg = fmaxf(mxg, __shfl_xor(mxg, 32));
            const float mnew = fmaxf(mrun, mxg);
            const float corr = __builtin_amdgcn_exp2f(mrun - mnew);
            mrun = mnew;
            lsum *= corr;
#pragma unroll
            for (int d = 0; d < 4; ++d) {
                ctx[d][0] *= corr; ctx[d][1] *= corr;
                ctx[d][2] *= corr; ctx[d][3] *= corr;
            }
        }

#pragma unroll
        for (int i = 0; i < 16; ++i) pv[i] = __builtin_amdgcn_exp2f(pv[i] - mrun);
        // per-lane partial row-sum (cross-hi reduce deferred to epilogue)
        float ts[8];
#pragma unroll
        for (int i = 0; i < 8; ++i) ts[i] = pv[i] + pv[i + 8];
#pragma unroll
        for (int i = 0; i < 4; ++i) ts[i] = ts[i] + ts[i + 4];
        lsum += (ts[0] + ts[1]) + (ts[2] + ts[3]);

        // ---- pack P to f16x2 dwords: ph[fj][r2] = kv pair (fj*16+hi*4+2r2, +1)
        int ph[4][2];
#pragma unroll
        for (int fj = 0; fj < 4; ++fj)
#pragma unroll
            for (int r2 = 0; r2 < 2; ++r2) {
                f16x2 hpair = {(f16)pv[fj * 4 + 2 * r2], (f16)pv[fj * 4 + 2 * r2 + 1]};
                ph[fj][r2] = __builtin_bit_cast(int, hpair);
            }

        // ---- redistribute to B-frag: lane needs kv = kc*32 + hi*8 + (0..7)
        f16x8 pb[2];
#pragma unroll
        for (int kc = 0; kc < 2; ++kc) {
            i32x4 dw;
#pragma unroll
            for (int j2 = 0; j2 < 4; ++j2) {
                const int idx = (j2 < 2) ? idx0 : idx1;
                int vA = __shfl(ph[2 * kc][j2 & 1], idx);
                int vB = __shfl(ph[2 * kc + 1][j2 & 1], idx);
                dw[j2] = (hi & 2) ? vB : vA;
            }
            pb[kc] = __builtin_bit_cast(f16x8, dw);
        }

        // ---- PV: ctx^T[d][q] += V^T[d][kv] * P^T[kv][q] ----
        __builtin_amdgcn_s_setprio(1);
#pragma unroll
        for (int df = 0; df < 4; ++df) {
            ctx[df] = MFMA(vf[df][0], pb[0], ctx[df]);
            ctx[df] = MFMA(vf[df][1], pb[1], ctx[df]);
        }
        __builtin_amdgcn_s_setprio(0);

        // advance K rows (+64) and V^T cols (+64)
#pragma unroll
        for (int fj = 0; fj < 4; ++fj) kp[fj] += 64 * 1024;
#pragma unroll
        for (int df = 0; df < 4; ++df) vp[df] += 64;
    }

    // epilogue: cross-hi row-sum, then lane-local normalize; lane owns
    // ctx^T[d = df*16 + hi*4 + r][q = qw0 + lo]
    float lt = lsum + __shfl_xor(lsum, 16);
    lt += __shfl_xor(lt, 32);
    const float inv = 1.0f / lt;
#pragma unroll
    for (int df = 0; df < 4; ++df) {
        f16x4 o = {(f16)(ctx[df][0] * inv), (f16)(ctx[df][1] * inv),
                   (f16)(ctx[df][2] * inv), (f16)(ctx[df][3] * inv)};
        *(f16x4*)(CTX + (size_t)(b * 2048 + qw0 + lo) * 1024 + h * 64 + df * 16 + hi * 4) = o;
    }
}

// ---------------------------------------------------------------------------
// Kernel 4: output projection GEMM, BM=64 x BN=128 (grid 64x8 = 512 blocks
// = 2 blocks/CU so the barrier drain overlaps across blocks).
// C[m][n] = sum_k A[m][k]*Wo[n][k] + bias[n].  4 waves, each 64x32 out.
// ---------------------------------------------------------------------------
__global__ void gemm_proj(const f16* __restrict__ A, const f16* __restrict__ Bw,
                          float* __restrict__ Co, const float* __restrict__ bias) {
    __shared__ __align__(16) f16 As[64 * 64];
    __shared__ __align__(16) f16 Bs[128 * 64];
    const int tid = threadIdx.x;
    const int lane = tid & 63, w = tid >> 6;
    const int lo = lane & 15, hi = lane >> 4;
    const int m0 = blockIdx.x * 64, n0 = blockIdx.y * 128;
    const char* Ab = (const char*)A;
    const char* Bb = (const char*)Bw;

    f32x4 acc[4][2];
#pragma unroll
    for (int i = 0; i < 4; ++i) {
        acc[i][0] = (f32x4){0.f, 0.f, 0.f, 0.f};
        acc[i][1] = (f32x4){0.f, 0.f, 0.f, 0.f};
    }

    for (int kt = 0; kt < 16; ++kt) {
        const int kb = kt * 128;
#pragma unroll
        for (int rr = 0; rr < 2; ++rr) {  // A tile: 64 rows x 128 B
            int o = rr * 4096 + tid * 16;
            int row = o >> 7, colB = o & 127;
            gload16(Ab + (size_t)(m0 + row) * 2048 + kb + colB, (char*)As + o);
        }
#pragma unroll
        for (int rr = 0; rr < 4; ++rr) {  // B tile: 128 rows x 128 B
            int o = rr * 4096 + tid * 16;
            int row = o >> 7, colB = o & 127;
            gload16(Bb + (size_t)(n0 + row) * 2048 + kb + colB, (char*)Bs + o);
        }
        __syncthreads();
#pragma unroll
        for (int kc = 0; kc < 2; ++kc) {
            f16x8 af[4], bf[2];
#pragma unroll
            for (int f = 0; f < 4; ++f)
                af[f] = *(const f16x8*)(As + (f * 16 + lo) * 64 + kc * 32 + hi * 8);
#pragma unroll
            for (int f = 0; f < 2; ++f)
                bf[f] = *(const f16x8*)(Bs + (w * 32 + f * 16 + lo) * 64 + kc * 32 + hi * 8);
#pragma unroll
            for (int i = 0; i < 4; ++i)
#pragma unroll
                for (int j = 0; j < 2; ++j) acc[i][j] = MFMA(af[i], bf[j], acc[i][j]);
        }
        __syncthreads();
    }

    const int mbase = m0 + hi * 4;
    const int nbase = n0 + w * 32 + lo;
#pragma unroll
    for (int j = 0; j < 2; ++j) {
        float bj = bias[nbase + j * 16];
#pragma unroll
        for (int i = 0; i < 4; ++i)
#pragma unroll
            for (int r = 0; r < 4; ++r)
                Co[(size_t)(mbase + i * 16 + r) * 1024 + nbase + j * 16] =
                    acc[i][j][r] + bj;
    }
}

// ---------------------------------------------------------------------------
extern "C" void kernel_launch(void* const* d_in, const int* in_sizes, int n_in,
                              void* d_out, int out_size, void* d_ws, size_t ws_size,
                              hipStream_t stream) {
    const float* x = (const float*)d_in[0];
    const float* wq = (const float*)d_in[1];
    const float* wk = (const float*)d_in[2];
    const float* wv = (const float*)d_in[3];
    const float* wo = (const float*)d_in[4];
    const float* bo = (const float*)d_in[5];

    const size_t M1 = 1024 * 1024;
    f16* VT = (f16*)d_ws;          // 4M f16 (8 MB): V transposed [b*1024+n][2048]
    f16* Wh = VT + 4 * M1;         // 4M f16: Wq|Wk|Wv|Wo
    f16* QKV = Wh + 4 * M1;        // Q (4M) | K (4M)
    f16* Xb = QKV + 8 * M1;        // x cast; region later reused as CTX
    f16* Q = QKV;
    f16* K = QKV + 4 * M1;
    f16* CTX = QKV + 8 * M1;       // alias Xb: x dead after QKV GEMM
    float* out = (float*)d_out;

    cast_all<<<dim3(8192), dim3(256), 0, stream>>>(x, wq, wk, wv, wo, Xb, Wh);
    gemm_bt<false><<<dim3(32, 8, 3), dim3(256), 0, stream>>>(Xb, Wh, QKV, VT, nullptr, nullptr);
    attn<<<dim3(32, 32), dim3(256), 0, stream>>>(Q, K, VT, CTX);
    gemm_proj<<<dim3(64, 8), dim3(256), 0, stream>>>(CTX, Wh + 3 * M1, out, bo);
}

// Round 8
// 194.343 us; speedup vs baseline: 1.3801x; 1.3801x over previous
//
#include <hip/hip_runtime.h>

typedef _Float16 f16;
typedef _Float16 f16x2 __attribute__((ext_vector_type(2)));
typedef _Float16 f16x4 __attribute__((ext_vector_type(4)));
typedef _Float16 f16x8 __attribute__((ext_vector_type(8)));
typedef float f32x4 __attribute__((ext_vector_type(4)));
typedef int i32x4 __attribute__((ext_vector_type(4)));

#define MFMA(a, b, c) __builtin_amdgcn_mfma_f32_16x16x32_f16((a), (b), (c), 0, 0, 0)

typedef __attribute__((address_space(1))) const void gvoid;
typedef __attribute__((address_space(3))) void lvoid;

__device__ __forceinline__ void gload16(const void* g, void* l) {
    __builtin_amdgcn_global_load_lds((gvoid*)g, (lvoid*)l, 16, 0, 0);
}

// ---------------------------------------------------------------------------
// Kernel 1: cast f32 -> f16 for in_data (4M elems) and 4 weights (4x1M elems)
// ---------------------------------------------------------------------------
__global__ void cast_all(const float* __restrict__ x,
                         const float* __restrict__ w0, const float* __restrict__ w1,
                         const float* __restrict__ w2, const float* __restrict__ w3,
                         f16* __restrict__ xb, f16* __restrict__ wb) {
    const int NX = 4096 * 1024;
    int i = (blockIdx.x * 256 + threadIdx.x) * 4;
    if (i < NX) {
        float4 v = *(const float4*)(x + i);
        f16x4 o = {(f16)v.x, (f16)v.y, (f16)v.z, (f16)v.w};
        *(f16x4*)(xb + i) = o;
    } else {
        int j = i - NX;  // [0, 4M)
        const float* s = (j < (1 << 20)) ? w0 : (j < (2 << 20)) ? w1
                       : (j < (3 << 20)) ? w2 : w3;
        int loc = j & ((1 << 20) - 1);
        float4 v = *(const float4*)(s + loc);
        f16x4 o = {(f16)v.x, (f16)v.y, (f16)v.z, (f16)v.w};
        *(f16x4*)(wb + j) = o;
    }
}

// ---------------------------------------------------------------------------
// Kernel 2/4: GEMM C[m][n] = sum_k A[m][k]*B[n][k], BM=64 BN=128 BK=64.
// Grid (64, 8, z): 6 blocks/CU (24 KB LDS) so CU-level overlap hides the
// 2-barrier-per-kt stall. 4 waves, each 64x32 out.
// !FINAL epilogues: z=0 -> Q scaled 0.125*log2(e); z=1 -> K; z=2 -> V
// written TRANSPOSED into VT[b*1024+n][2048]. FINAL: f32 out + bias.
// ---------------------------------------------------------------------------
template <bool FINAL>
__global__ void gemm64(const f16* __restrict__ A, const f16* __restrict__ Bw,
                       f16* __restrict__ Cf, f16* __restrict__ VTo,
                       float* __restrict__ Co, const float* __restrict__ bias) {
    __shared__ __align__(16) f16 As[64 * 64];
    __shared__ __align__(16) f16 Bs[128 * 64];
    const int tid = threadIdx.x;
    const int lane = tid & 63, w = tid >> 6;
    const int lo = lane & 15, hi = lane >> 4;
    const int m0 = blockIdx.x * 64, n0 = blockIdx.y * 128;
    const char* Ab = (const char*)A;
    const char* Bb = (const char*)(Bw + (size_t)blockIdx.z * (1024 * 1024));

    f32x4 acc[4][2];
#pragma unroll
    for (int i = 0; i < 4; ++i) {
        acc[i][0] = (f32x4){0.f, 0.f, 0.f, 0.f};
        acc[i][1] = (f32x4){0.f, 0.f, 0.f, 0.f};
    }

    for (int kt = 0; kt < 16; ++kt) {
        const int kb = kt * 128;  // byte offset along K (64 f16)
#pragma unroll
        for (int rr = 0; rr < 2; ++rr) {  // A tile: 64 rows x 128 B
            int o = rr * 4096 + tid * 16;
            int row = o >> 7, colB = o & 127;
            gload16(Ab + (size_t)(m0 + row) * 2048 + kb + colB, (char*)As + o);
        }
#pragma unroll
        for (int rr = 0; rr < 4; ++rr) {  // B tile: 128 rows x 128 B
            int o = rr * 4096 + tid * 16;
            int row = o >> 7, colB = o & 127;
            gload16(Bb + (size_t)(n0 + row) * 2048 + kb + colB, (char*)Bs + o);
        }
        __syncthreads();
#pragma unroll
        for (int kc = 0; kc < 2; ++kc) {
            f16x8 af[4], bf[2];
#pragma unroll
            for (int f = 0; f < 4; ++f)
                af[f] = *(const f16x8*)(As + (f * 16 + lo) * 64 + kc * 32 + hi * 8);
#pragma unroll
            for (int f = 0; f < 2; ++f)
                bf[f] = *(const f16x8*)(Bs + (w * 32 + f * 16 + lo) * 64 + kc * 32 + hi * 8);
#pragma unroll
            for (int i = 0; i < 4; ++i)
#pragma unroll
                for (int j = 0; j < 2; ++j) acc[i][j] = MFMA(af[i], bf[j], acc[i][j]);
        }
        __syncthreads();
    }

    const int mbase = m0 + hi * 4;
    const int nbase = n0 + w * 32 + lo;
    if (FINAL) {
#pragma unroll
        for (int j = 0; j < 2; ++j) {
            float bj = bias[nbase + j * 16];
#pragma unroll
            for (int i = 0; i < 4; ++i)
#pragma unroll
                for (int r = 0; r < 4; ++r)
                    Co[(size_t)(mbase + i * 16 + r) * 1024 + nbase + j * 16] =
                        acc[i][j][r] + bj;
        }
    } else if (blockIdx.z == 2) {
        // V written transposed: VT[(b*1024 + n)][s],  m = b*2048+s
#pragma unroll
        for (int i = 0; i < 4; ++i)
#pragma unroll
            for (int j = 0; j < 2; ++j)
#pragma unroll
                for (int r = 0; r < 4; ++r) {
                    int m = mbase + i * 16 + r, n = nbase + j * 16;
                    VTo[(size_t)((m >> 11) * 1024 + n) * 2048 + (m & 2047)] =
                        (f16)acc[i][j][r];
                }
    } else {
        // z==0: fold 1/sqrt(64) * log2(e) into Q (softmax runs in exp2 domain)
        const float osc = (blockIdx.z == 0) ? 0.18033688f : 1.0f;
        f16* Cz = Cf + (size_t)blockIdx.z * (4096 * 1024);
#pragma unroll
        for (int i = 0; i < 4; ++i)
#pragma unroll
            for (int j = 0; j < 2; ++j)
#pragma unroll
                for (int r = 0; r < 4; ++r)
                    Cz[(size_t)(mbase + i * 16 + r) * 1024 + nbase + j * 16] =
                        (f16)(acc[i][j][r] * osc);
    }
}

// ---------------------------------------------------------------------------
// Kernel 3: causal flash attention, KVBLK=128 (half the barriers of r6).
// Round-6 proven race-free sync: statically distinct double buffers, ONE
// __syncthreads per kv-step, stage(t+1) issued right after the barrier so
// its loads fly under compute(t) and are drained by the next barrier.
//  - swapped QK^T: lane owns q=lo, kv = fj*16 + hi*4 + r (fj 0..7)
//  - exp2-domain softmax, defer-max (thr=8), per-lane partial row-sum
//  - P redistributed to PV B-fragments in registers (32 shfl + selects)
//  - PV = MFMA(V_frag, P_frag) -> ctx^T; corr & 1/l lane-local
// LDS 64 KB -> 2 blocks/CU. Grid (32 bh, 32 qt reversed) -> XCD = bh%8.
// ---------------------------------------------------------------------------
__global__ __launch_bounds__(256) void attn(const f16* __restrict__ Q,
                                            const f16* __restrict__ K,
                                            const f16* __restrict__ VT,
                                            f16* __restrict__ CTX) {
    __shared__ __align__(16) f16 K0[128 * 64];   // [kv 128][d 64]
    __shared__ __align__(16) f16 K1[128 * 64];
    __shared__ __align__(16) f16 V0[64 * 128];   // [d 64][kv 128]
    __shared__ __align__(16) f16 V1[64 * 128];
    const int tid = threadIdx.x;
    const int lane = tid & 63, w = tid >> 6;
    const int lo = lane & 15, hi = lane >> 4;
    const int bh = blockIdx.x;
    const int qt = 31 - blockIdx.y;  // heavy tiles dispatch first
    const int b = bh >> 4, h = bh & 15;
    const int qw0 = qt * 64 + w * 16;
    const int qglob = qw0 + lo;
    const int nt = qt / 2 + 1;       // # of 128-kv steps (mask only on last)

    // Q fragments (B-operand of swapped QK^T): col=q=lo, k=kc*32+hi*8+j
    const f16* qrow = Q + (size_t)(b * 2048 + qw0 + lo) * 1024 + h * 64 + hi * 8;
    const f16x8 qa0 = *(const f16x8*)(qrow);
    const f16x8 qa1 = *(const f16x8*)(qrow + 32);

    // ctx^T: lane owns d = df*16 + hi*4 + r, q = qw0 + lo
    f32x4 ctx[4];
#pragma unroll
    for (int d = 0; d < 4; ++d) ctx[d] = (f32x4){0.f, 0.f, 0.f, 0.f};
    float mrun = -3e38f, lsum = 0.f;

    // shfl indices for the P redistribution (dest (hi,j2) <- src hi-group)
    const int idx0 = (2 * (hi & 1)) * 16 + lo;   // j2 in {0,1}
    const int idx1 = idx0 + 16;                  // j2 in {2,3}

    const char* Kb = (const char*)K;
    const char* Vb = (const char*)VT;

    auto stage = [&](f16* Kd, f16* Vd, int t) {
        const int kv0 = t * 128;
        // K tile: 128 rows x 128 B, pre-swizzled source, linear LDS dest
#pragma unroll
        for (int rr = 0; rr < 4; ++rr) {
            int o = rr * 4096 + tid * 16;
            int row = o >> 7;
            int colB = (o & 127) ^ ((row & 7) << 4);
            gload16(Kb + (size_t)(b * 2048 + kv0 + row) * 2048 + h * 128 + colB,
                    (char*)Kd + o);
        }
        // V^T tile: 64 rows x 256 B
#pragma unroll
        for (int rr = 0; rr < 4; ++rr) {
            int o = rr * 4096 + tid * 16;
            int row = o >> 8;
            int colB = (o & 255) ^ ((row & 7) << 4);
            gload16(Vb + (size_t)(b * 1024 + h * 64 + row) * 4096 + (size_t)kv0 * 2 + colB,
                    (char*)Vd + o);
        }
    };

    auto compute = [&](const f16* Klb, const f16* Vlb, int t) {
        // ---- QK^T swapped: lane owns q=lo, kv = fj*16 + hi*4 + r ----
        f32x4 s4[8];
        __builtin_amdgcn_s_setprio(1);
#pragma unroll
        for (int fj = 0; fj < 8; ++fj) {
            f32x4 a = (f32x4){0.f, 0.f, 0.f, 0.f};
            const int kv = fj * 16 + lo;  // A-frag row
#pragma unroll
            for (int kc = 0; kc < 2; ++kc) {
                const int cb = (kc * 64 + hi * 16) ^ ((kv & 7) << 4);
                f16x8 kf = *(const f16x8*)((const char*)Klb + kv * 128 + cb);
                a = MFMA(kf, kc ? qa1 : qa0, a);
            }
            s4[fj] = a;
        }
        __builtin_amdgcn_s_setprio(0);

        // ---- softmax (exp2 domain), defer-max ----
        float pv[32];
        if (t == nt - 1) {  // only the diagonal step masks (wave-uniform)
#pragma unroll
            for (int fj = 0; fj < 8; ++fj)
#pragma unroll
                for (int r = 0; r < 4; ++r) {
                    const int kvg = t * 128 + fj * 16 + hi * 4 + r;
                    pv[fj * 4 + r] = (kvg > qglob) ? -1e38f : s4[fj][r];
                }
        } else {
#pragma unroll
            for (int fj = 0; fj < 8; ++fj)
#pragma unroll
                for (int r = 0; r < 4; ++r) pv[fj * 4 + r] = s4[fj][r];
        }

        // lane-local max of 32 (tree)
        float tm[16];
#pragma unroll
        for (int i = 0; i < 16; ++i) tm[i] = fmaxf(pv[i], pv[i + 16]);
#pragma unroll
        for (int i = 0; i < 8; ++i) tm[i] = fmaxf(tm[i], tm[i + 8]);
#pragma unroll
        for (int i = 0; i < 4; ++i) tm[i] = fmaxf(tm[i], tm[i + 4]);
        const float mxl = fmaxf(fmaxf(tm[0], tm[1]), fmaxf(tm[2], tm[3]));

        if (__any(mxl > mrun + 8.0f)) {  // rescale path (rare after warmup)
            float mxg = fmaxf(mxl, __shfl_xor(mxl, 16));
            mxg = fmaxf(mxg, __shfl_xor(mxg, 32));
            const float mnew = fmaxf(mrun, mxg);
            const float corr = __builtin_amdgcn_exp2f(mrun - mnew);
            mrun = mnew;
            lsum *= corr;
#pragma unroll
            for (int d = 0; d < 4; ++d) {
                ctx[d][0] *= corr; ctx[d][1] *= corr;
                ctx[d][2] *= corr; ctx[d][3] *= corr;
            }
        }

#pragma unroll
        for (int i = 0; i < 32; ++i) pv[i] = __builtin_amdgcn_exp2f(pv[i] - mrun);
        // per-lane partial row-sum (cross-hi reduce deferred to epilogue)
        float ts[16];
#pragma unroll
        for (int i = 0; i < 16; ++i) ts[i] = pv[i] + pv[i + 16];
#pragma unroll
        for (int i = 0; i < 8; ++i) ts[i] = ts[i] + ts[i + 8];
#pragma unroll
        for (int i = 0; i < 4; ++i) ts[i] = ts[i] + ts[i + 4];
        lsum += (ts[0] + ts[1]) + (ts[2] + ts[3]);

        // ---- pack P to f16x2 dwords: ph[fj][r2] = kv pair (fj*16+hi*4+2r2, +1)
        int ph[8][2];
#pragma unroll
        for (int fj = 0; fj < 8; ++fj)
#pragma unroll
            for (int r2 = 0; r2 < 2; ++r2) {
                f16x2 hpair = {(f16)pv[fj * 4 + 2 * r2], (f16)pv[fj * 4 + 2 * r2 + 1]};
                ph[fj][r2] = __builtin_bit_cast(int, hpair);
            }

        // ---- redistribute to B-frag: lane needs kv = kc*32 + hi*8 + (0..7)
        // dword(kc,j2) = shfl(ph[2kc + (hi>>1)][j2&1], (2(hi&1)+(j2>>1))*16+lo)
        f16x8 pb[4];
#pragma unroll
        for (int kc = 0; kc < 4; ++kc) {
            i32x4 dw;
#pragma unroll
            for (int j2 = 0; j2 < 4; ++j2) {
                const int idx = (j2 < 2) ? idx0 : idx1;
                int vA = __shfl(ph[2 * kc][j2 & 1], idx);
                int vB = __shfl(ph[2 * kc + 1][j2 & 1], idx);
                dw[j2] = (hi & 2) ? vB : vA;
            }
            pb[kc] = __builtin_bit_cast(f16x8, dw);
        }

        // ---- PV: ctx^T[d][q] += V^T[d][kv] * P^T[kv][q] ----
        __builtin_amdgcn_s_setprio(1);
#pragma unroll
        for (int df = 0; df < 4; ++df) {
            const int d = df * 16 + lo;  // A-frag row
#pragma unroll
            for (int kc = 0; kc < 4; ++kc) {
                const int cb = (kc * 64 + hi * 16) ^ ((d & 7) << 4);
                f16x8 vf = *(const f16x8*)((const char*)Vlb + d * 256 + cb);
                ctx[df] = MFMA(vf, pb[kc], ctx[df]);
            }
        }
        __builtin_amdgcn_s_setprio(0);
    };

    stage(&K0[0], &V0[0], 0);
    for (int t = 0; t < nt; ++t) {
        __syncthreads();  // drains stage(t) loads (all waves) + full fence
        if ((t & 1) == 0) {
            if (t < nt - 1) stage(&K1[0], &V1[0], t + 1);
            compute(&K0[0], &V0[0], t);
        } else {
            if (t < nt - 1) stage(&K0[0], &V0[0], t + 1);
            compute(&K1[0], &V1[0], t);
        }
    }

    // epilogue: cross-hi row-sum, then lane-local normalize; lane owns
    // ctx^T[d = df*16 + hi*4 + r][q = qw0 + lo]
    float lt = lsum + __shfl_xor(lsum, 16);
    lt += __shfl_xor(lt, 32);
    const float inv = 1.0f / lt;
#pragma unroll
    for (int df = 0; df < 4; ++df) {
        f16x4 o = {(f16)(ctx[df][0] * inv), (f16)(ctx[df][1] * inv),
                   (f16)(ctx[df][2] * inv), (f16)(ctx[df][3] * inv)};
        *(f16x4*)(CTX + (size_t)(b * 2048 + qw0 + lo) * 1024 + h * 64 + df * 16 + hi * 4) = o;
    }
}

// ---------------------------------------------------------------------------
extern "C" void kernel_launch(void* const* d_in, const int* in_sizes, int n_in,
                              void* d_out, int out_size, void* d_ws, size_t ws_size,
                              hipStream_t stream) {
    const float* x = (const float*)d_in[0];
    const float* wq = (const float*)d_in[1];
    const float* wk = (const float*)d_in[2];
    const float* wv = (const float*)d_in[3];
    const float* wo = (const float*)d_in[4];
    const float* bo = (const float*)d_in[5];

    const size_t M1 = 1024 * 1024;
    f16* VT = (f16*)d_ws;          // 4M f16 (8 MB): V transposed [b*1024+n][2048]
    f16* Wh = VT + 4 * M1;         // 4M f16: Wq|Wk|Wv|Wo
    f16* QKV = Wh + 4 * M1;        // Q (4M) | K (4M)
    f16* Xb = QKV + 8 * M1;        // x cast; region later reused as CTX
    f16* Q = QKV;
    f16* K = QKV + 4 * M1;
    f16* CTX = QKV + 8 * M1;       // alias Xb: x dead after QKV GEMM
    float* out = (float*)d_out;

    cast_all<<<dim3(8192), dim3(256), 0, stream>>>(x, wq, wk, wv, wo, Xb, Wh);
    gemm64<false><<<dim3(64, 8, 3), dim3(256), 0, stream>>>(Xb, Wh, QKV, VT, nullptr, nullptr);
    attn<<<dim3(32, 32), dim3(256), 0, stream>>>(Q, K, VT, CTX);
    gemm64<true><<<dim3(64, 8, 1), dim3(256), 0, stream>>>(CTX, Wh + 3 * M1, nullptr, nullptr, out, bo);
}

// Round 9
// 185.778 us; speedup vs baseline: 1.4437x; 1.0461x over previous
//
#include <hip/hip_runtime.h>

typedef _Float16 f16;
typedef _Float16 f16x2 __attribute__((ext_vector_type(2)));
typedef _Float16 f16x4 __attribute__((ext_vector_type(4)));
typedef _Float16 f16x8 __attribute__((ext_vector_type(8)));
typedef float f32x4 __attribute__((ext_vector_type(4)));
typedef int i32x4 __attribute__((ext_vector_type(4)));

#define MFMA(a, b, c) __builtin_amdgcn_mfma_f32_16x16x32_f16((a), (b), (c), 0, 0, 0)

typedef __attribute__((address_space(1))) const void gvoid;
typedef __attribute__((address_space(3))) void lvoid;

__device__ __forceinline__ void gload16(const void* g, void* l) {
    __builtin_amdgcn_global_load_lds((gvoid*)g, (lvoid*)l, 16, 0, 0);
}

// ---------------------------------------------------------------------------
// Kernel 1: cast f32 -> f16 for in_data (4M elems) and 4 weights (4x1M elems)
// ---------------------------------------------------------------------------
__global__ void cast_all(const float* __restrict__ x,
                         const float* __restrict__ w0, const float* __restrict__ w1,
                         const float* __restrict__ w2, const float* __restrict__ w3,
                         f16* __restrict__ xb, f16* __restrict__ wb) {
    const int NX = 4096 * 1024;
    int i = (blockIdx.x * 256 + threadIdx.x) * 4;
    if (i < NX) {
        float4 v = *(const float4*)(x + i);
        f16x4 o = {(f16)v.x, (f16)v.y, (f16)v.z, (f16)v.w};
        *(f16x4*)(xb + i) = o;
    } else {
        int j = i - NX;  // [0, 4M)
        const float* s = (j < (1 << 20)) ? w0 : (j < (2 << 20)) ? w1
                       : (j < (3 << 20)) ? w2 : w3;
        int loc = j & ((1 << 20) - 1);
        float4 v = *(const float4*)(s + loc);
        f16x4 o = {(f16)v.x, (f16)v.y, (f16)v.z, (f16)v.w};
        *(f16x4*)(wb + j) = o;
    }
}

// ---------------------------------------------------------------------------
// Kernel 2: FUSED QKV GEMM. C_z[m][n] = sum_k X[m][k]*W_z[n][k], z=0,1,2.
// BM=128, BN=64, BK=64; A-tile staged ONCE per kt serving 3 B-tiles ->
// 3x MFMA per barrier. Double-buffered (r6-proven sync: static distinct
// buffers, one __syncthreads/kt, stage(t+1) under compute(t)). LDS tiles
// XOR-swizzled (colB ^ ((row&7)<<4), both sides). Grid (32,16) = 2/CU.
// Epilogues: z=0 -> Q * 0.125*log2(e); z=1 -> K; z=2 -> V transposed into
// VT[b*1024+n][2048].
// ---------------------------------------------------------------------------
__global__ __launch_bounds__(256) void gemm_qkv(const f16* __restrict__ A,
                                                const f16* __restrict__ W,
                                                f16* __restrict__ Qo,
                                                f16* __restrict__ Ko,
                                                f16* __restrict__ VTo) {
    __shared__ __align__(16) f16 A0[128 * 64];
    __shared__ __align__(16) f16 A1[128 * 64];
    __shared__ __align__(16) f16 B0[3][64 * 64];
    __shared__ __align__(16) f16 B1[3][64 * 64];
    const int tid = threadIdx.x;
    const int lane = tid & 63, w = tid >> 6;
    const int lo = lane & 15, hi = lane >> 4;
    const int wr = w >> 1, wc = w & 1;
    const int m0 = blockIdx.x * 128, n0 = blockIdx.y * 64;
    const char* Ab = (const char*)A;
    const char* Wb = (const char*)W;

    f32x4 acc[3][4][2];
#pragma unroll
    for (int z = 0; z < 3; ++z)
#pragma unroll
        for (int i = 0; i < 4; ++i)
#pragma unroll
            for (int j = 0; j < 2; ++j) acc[z][i][j] = (f32x4){0.f, 0.f, 0.f, 0.f};

    auto stage = [&](f16* Ad, f16 (*Bd)[64 * 64], int kt) {
        const int kb = kt * 128;  // byte offset along K
#pragma unroll
        for (int rr = 0; rr < 4; ++rr) {  // A: 128 rows x 128 B
            int o = rr * 4096 + tid * 16;
            int row = o >> 7;
            int colB = (o & 127) ^ ((row & 7) << 4);
            gload16(Ab + (size_t)(m0 + row) * 2048 + kb + colB, (char*)Ad + o);
        }
#pragma unroll
        for (int z = 0; z < 3; ++z)
#pragma unroll
            for (int rr = 0; rr < 2; ++rr) {  // B_z: 64 rows x 128 B
                int o = rr * 4096 + tid * 16;
                int row = o >> 7;
                int colB = (o & 127) ^ ((row & 7) << 4);
                gload16(Wb + (size_t)z * 2097152 + (size_t)(n0 + row) * 2048 + kb + colB,
                        (char*)&Bd[z][0] + o);
            }
    };

    auto compute = [&](const f16* Al, const f16 (*Bl)[64 * 64]) {
#pragma unroll
        for (int kc = 0; kc < 2; ++kc) {
            f16x8 af[4];
#pragma unroll
            for (int f = 0; f < 4; ++f) {
                const int row = wr * 64 + f * 16 + lo;
                const int cb = (kc * 64 + hi * 16) ^ ((row & 7) << 4);
                af[f] = *(const f16x8*)((const char*)Al + row * 128 + cb);
            }
#pragma unroll
            for (int z = 0; z < 3; ++z) {
                f16x8 bf[2];
#pragma unroll
                for (int f = 0; f < 2; ++f) {
                    const int row = wc * 32 + f * 16 + lo;
                    const int cb = (kc * 64 + hi * 16) ^ ((row & 7) << 4);
                    bf[f] = *(const f16x8*)((const char*)&Bl[z][0] + row * 128 + cb);
                }
#pragma unroll
                for (int i = 0; i < 4; ++i)
#pragma unroll
                    for (int j = 0; j < 2; ++j)
                        acc[z][i][j] = MFMA(af[i], bf[j], acc[z][i][j]);
            }
        }
    };

    stage(&A0[0], B0, 0);
    for (int kt = 0; kt < 16; ++kt) {
        __syncthreads();  // drains stage(kt) loads + full fence
        if ((kt & 1) == 0) {
            if (kt < 15) stage(&A1[0], B1, kt + 1);
            compute(&A0[0], B0);
        } else {
            if (kt < 15) stage(&A0[0], B0, kt + 1);
            compute(&A1[0], B1);
        }
    }

    const int mb = m0 + wr * 64 + hi * 4;
    const int nb = n0 + wc * 32 + lo;
#pragma unroll
    for (int i = 0; i < 4; ++i)
#pragma unroll
        for (int j = 0; j < 2; ++j)
#pragma unroll
            for (int r = 0; r < 4; ++r) {
                const int m = mb + i * 16 + r, n = nb + j * 16;
                // z=0: Q scaled into exp2 domain
                Qo[(size_t)m * 1024 + n] = (f16)(acc[0][i][j][r] * 0.18033688f);
                // z=1: K
                Ko[(size_t)m * 1024 + n] = (f16)acc[1][i][j][r];
                // z=2: V transposed: VT[(b*1024 + n)][s], m = b*2048+s
                VTo[(size_t)((m >> 11) * 1024 + n) * 2048 + (m & 2047)] =
                    (f16)acc[2][i][j][r];
            }
}

// ---------------------------------------------------------------------------
// Kernel 3: causal flash attention — EXACT round-6 config (proven 50.4 us).
// KVBLK=64, statically-distinct double buffers, one __syncthreads per step.
// swapped QK^T, exp2-domain softmax, defer-max, register-P PV -> ctx^T.
// Grid (32 bh, 32 qt reversed) -> XCD = bh%8. 4 waves x 16 q-rows.
// ---------------------------------------------------------------------------
__global__ __launch_bounds__(256) void attn(const f16* __restrict__ Q,
                                            const f16* __restrict__ K,
                                            const f16* __restrict__ VT,
                                            f16* __restrict__ CTX) {
    __shared__ __align__(16) f16 K0[64 * 64];
    __shared__ __align__(16) f16 K1[64 * 64];
    __shared__ __align__(16) f16 V0[64 * 64];
    __shared__ __align__(16) f16 V1[64 * 64];
    const int tid = threadIdx.x;
    const int lane = tid & 63, w = tid >> 6;
    const int lo = lane & 15, hi = lane >> 4;
    const int bh = blockIdx.x;
    const int qt = 31 - blockIdx.y;  // heavy tiles dispatch first
    const int b = bh >> 4, h = bh & 15;
    const int qw0 = qt * 64 + w * 16;
    const int qglob = qw0 + lo;

    const f16* qrow = Q + (size_t)(b * 2048 + qw0 + lo) * 1024 + h * 64 + hi * 8;
    const f16x8 qa0 = *(const f16x8*)(qrow);
    const f16x8 qa1 = *(const f16x8*)(qrow + 32);

    f32x4 ctx[4];
#pragma unroll
    for (int d = 0; d < 4; ++d) ctx[d] = (f32x4){0.f, 0.f, 0.f, 0.f};
    float mrun = -3e38f, lsum = 0.f;

    const int idx0 = (2 * (hi & 1)) * 16 + lo;   // j2 in {0,1}
    const int idx1 = idx0 + 16;                  // j2 in {2,3}

    const char* Kb = (const char*)K;
    const char* Vb = (const char*)VT;

    auto stage = [&](f16* Kd, f16* Vd, int t) {
        const int kv0 = t * 64;
#pragma unroll
        for (int rr = 0; rr < 2; ++rr) {
            int o = rr * 4096 + tid * 16;
            int row = o >> 7;
            int colB = (o & 127) ^ ((row & 7) << 4);
            gload16(Kb + (size_t)(b * 2048 + kv0 + row) * 2048 + h * 128 + colB,
                    (char*)Kd + o);
            gload16(Vb + (size_t)(b * 1024 + h * 64 + row) * 4096 + (size_t)kv0 * 2 + colB,
                    (char*)Vd + o);
        }
    };

    auto compute = [&](const f16* Klb, const f16* Vlb, int t) {
        f32x4 s4[4];
        __builtin_amdgcn_s_setprio(1);
#pragma unroll
        for (int fj = 0; fj < 4; ++fj) {
            f32x4 a = (f32x4){0.f, 0.f, 0.f, 0.f};
            const int kv = fj * 16 + lo;
#pragma unroll
            for (int kc = 0; kc < 2; ++kc) {
                const int cb = (kc * 64 + hi * 16) ^ ((kv & 7) << 4);
                f16x8 kf = *(const f16x8*)((const char*)Klb + kv * 128 + cb);
                a = MFMA(kf, kc ? qa1 : qa0, a);
            }
            s4[fj] = a;
        }
        __builtin_amdgcn_s_setprio(0);

        float pv[16];
        if (t == qt) {
#pragma unroll
            for (int fj = 0; fj < 4; ++fj)
#pragma unroll
                for (int r = 0; r < 4; ++r) {
                    const int kvg = t * 64 + fj * 16 + hi * 4 + r;
                    pv[fj * 4 + r] = (kvg > qglob) ? -1e38f : s4[fj][r];
                }
        } else {
#pragma unroll
            for (int fj = 0; fj < 4; ++fj)
#pragma unroll
                for (int r = 0; r < 4; ++r) pv[fj * 4 + r] = s4[fj][r];
        }

        float tm[8];
#pragma unroll
        for (int i = 0; i < 8; ++i) tm[i] = fmaxf(pv[i], pv[i + 8]);
#pragma unroll
        for (int i = 0; i < 4; ++i) tm[i] = fmaxf(tm[i], tm[i + 4]);
        const float mxl = fmaxf(fmaxf(tm[0], tm[1]), fmaxf(tm[2], tm[3]));

        if (__any(mxl > mrun + 8.0f)) {
            float mxg = fmaxf(mxl, __shfl_xor(mxl, 16));
            mxg = fmaxf(mxg, __shfl_xor(mxg, 32));
            const float mnew = fmaxf(mrun, mxg);
            const float corr = __builtin_amdgcn_exp2f(mrun - mnew);
            mrun = mnew;
            lsum *= corr;
#pragma unroll
            for (int d = 0; d < 4; ++d) {
                ctx[d][0] *= corr; ctx[d][1] *= corr;
                ctx[d][2] *= corr; ctx[d][3] *= corr;
            }
        }

#pragma unroll
        for (int i = 0; i < 16; ++i) pv[i] = __builtin_amdgcn_exp2f(pv[i] - mrun);
        float ts[8];
#pragma unroll
        for (int i = 0; i < 8; ++i) ts[i] = pv[i] + pv[i + 8];
#pragma unroll
        for (int i = 0; i < 4; ++i) ts[i] = ts[i] + ts[i + 4];
        lsum += (ts[0] + ts[1]) + (ts[2] + ts[3]);

        int ph[4][2];
#pragma unroll
        for (int fj = 0; fj < 4; ++fj)
#pragma unroll
            for (int r2 = 0; r2 < 2; ++r2) {
                f16x2 hpair = {(f16)pv[fj * 4 + 2 * r2], (f16)pv[fj * 4 + 2 * r2 + 1]};
                ph[fj][r2] = __builtin_bit_cast(int, hpair);
            }

        f16x8 pb[2];
#pragma unroll
        for (int kc = 0; kc < 2; ++kc) {
            i32x4 dw;
#pragma unroll
            for (int j2 = 0; j2 < 4; ++j2) {
                const int idx = (j2 < 2) ? idx0 : idx1;
                int vA = __shfl(ph[2 * kc][j2 & 1], idx);
                int vB = __shfl(ph[2 * kc + 1][j2 & 1], idx);
                dw[j2] = (hi & 2) ? vB : vA;
            }
            pb[kc] = __builtin_bit_cast(f16x8, dw);
        }

        __builtin_amdgcn_s_setprio(1);
#pragma unroll
        for (int df = 0; df < 4; ++df) {
            const int d = df * 16 + lo;
#pragma unroll
            for (int kc = 0; kc < 2; ++kc) {
                const int cb = (kc * 64 + hi * 16) ^ ((d & 7) << 4);
                f16x8 vf = *(const f16x8*)((const char*)Vlb + d * 128 + cb);
                ctx[df] = MFMA(vf, pb[kc], ctx[df]);
            }
        }
        __builtin_amdgcn_s_setprio(0);
    };

    stage(&K0[0], &V0[0], 0);
    for (int t = 0; t <= qt; ++t) {
        __syncthreads();
        if ((t & 1) == 0) {
            if (t < qt) stage(&K1[0], &V1[0], t + 1);
            compute(&K0[0], &V0[0], t);
        } else {
            if (t < qt) stage(&K0[0], &V0[0], t + 1);
            compute(&K1[0], &V1[0], t);
        }
    }

    float lt = lsum + __shfl_xor(lsum, 16);
    lt += __shfl_xor(lt, 32);
    const float inv = 1.0f / lt;
#pragma unroll
    for (int df = 0; df < 4; ++df) {
        f16x4 o = {(f16)(ctx[df][0] * inv), (f16)(ctx[df][1] * inv),
                   (f16)(ctx[df][2] * inv), (f16)(ctx[df][3] * inv)};
        *(f16x4*)(CTX + (size_t)(b * 2048 + qw0 + lo) * 1024 + h * 64 + df * 16 + hi * 4) = o;
    }
}

// ---------------------------------------------------------------------------
// Kernel 4: output projection, BM=64 x BN=128, double-buffered (one
// __syncthreads/kt) + XOR-swizzled LDS. Grid (64,8) = 2/CU, LDS 48 KB.
// ---------------------------------------------------------------------------
__global__ __launch_bounds__(256) void gemm_proj(const f16* __restrict__ A,
                                                 const f16* __restrict__ Bw,
                                                 float* __restrict__ Co,
                                                 const float* __restrict__ bias) {
    __shared__ __align__(16) f16 A0[64 * 64];
    __shared__ __align__(16) f16 A1[64 * 64];
    __shared__ __align__(16) f16 B0[128 * 64];
    __shared__ __align__(16) f16 B1[128 * 64];
    const int tid = threadIdx.x;
    const int lane = tid & 63, w = tid >> 6;
    const int lo = lane & 15, hi = lane >> 4;
    const int m0 = blockIdx.x * 64, n0 = blockIdx.y * 128;
    const char* Ab = (const char*)A;
    const char* Bb = (const char*)Bw;

    f32x4 acc[4][2];
#pragma unroll
    for (int i = 0; i < 4; ++i) {
        acc[i][0] = (f32x4){0.f, 0.f, 0.f, 0.f};
        acc[i][1] = (f32x4){0.f, 0.f, 0.f, 0.f};
    }

    auto stage = [&](f16* Ad, f16* Bd, int kt) {
        const int kb = kt * 128;
#pragma unroll
        for (int rr = 0; rr < 2; ++rr) {  // A: 64 rows x 128 B
            int o = rr * 4096 + tid * 16;
            int row = o >> 7;
            int colB = (o & 127) ^ ((row & 7) << 4);
            gload16(Ab + (size_t)(m0 + row) * 2048 + kb + colB, (char*)Ad + o);
        }
#pragma unroll
        for (int rr = 0; rr < 4; ++rr) {  // B: 128 rows x 128 B
            int o = rr * 4096 + tid * 16;
            int row = o >> 7;
            int colB = (o & 127) ^ ((row & 7) << 4);
            gload16(Bb + (size_t)(n0 + row) * 2048 + kb + colB, (char*)Bd + o);
        }
    };

    auto compute = [&](const f16* Al, const f16* Bl) {
#pragma unroll
        for (int kc = 0; kc < 2; ++kc) {
            f16x8 af[4], bf[2];
#pragma unroll
            for (int f = 0; f < 4; ++f) {
                const int row = f * 16 + lo;
                const int cb = (kc * 64 + hi * 16) ^ ((row & 7) << 4);
                af[f] = *(const f16x8*)((const char*)Al + row * 128 + cb);
            }
#pragma unroll
            for (int f = 0; f < 2; ++f) {
                const int row = w * 32 + f * 16 + lo;
                const int cb = (kc * 64 + hi * 16) ^ ((row & 7) << 4);
                bf[f] = *(const f16x8*)((const char*)Bl + row * 128 + cb);
            }
#pragma unroll
            for (int i = 0; i < 4; ++i)
#pragma unroll
                for (int j = 0; j < 2; ++j) acc[i][j] = MFMA(af[i], bf[j], acc[i][j]);
        }
    };

    stage(&A0[0], &B0[0], 0);
    for (int kt = 0; kt < 16; ++kt) {
        __syncthreads();
        if ((kt & 1) == 0) {
            if (kt < 15) stage(&A1[0], &B1[0], kt + 1);
            compute(&A0[0], &B0[0]);
        } else {
            if (kt < 15) stage(&A0[0], &B0[0], kt + 1);
            compute(&A1[0], &B1[0]);
        }
    }

    const int mbase = m0 + hi * 4;
    const int nbase = n0 + w * 32 + lo;
#pragma unroll
    for (int j = 0; j < 2; ++j) {
        float bj = bias[nbase + j * 16];
#pragma unroll
        for (int i = 0; i < 4; ++i)
#pragma unroll
            for (int r = 0; r < 4; ++r)
                Co[(size_t)(mbase + i * 16 + r) * 1024 + nbase + j * 16] =
                    acc[i][j][r] + bj;
    }
}

// ---------------------------------------------------------------------------
extern "C" void kernel_launch(void* const* d_in, const int* in_sizes, int n_in,
                              void* d_out, int out_size, void* d_ws, size_t ws_size,
                              hipStream_t stream) {
    const float* x = (const float*)d_in[0];
    const float* wq = (const float*)d_in[1];
    const float* wk = (const float*)d_in[2];
    const float* wv = (const float*)d_in[3];
    const float* wo = (const float*)d_in[4];
    const float* bo = (const float*)d_in[5];

    const size_t M1 = 1024 * 1024;
    f16* VT = (f16*)d_ws;          // 4M f16 (8 MB): V transposed [b*1024+n][2048]
    f16* Wh = VT + 4 * M1;         // 4M f16: Wq|Wk|Wv|Wo
    f16* QKV = Wh + 4 * M1;        // Q (4M) | K (4M)
    f16* Xb = QKV + 8 * M1;        // x cast; region later reused as CTX
    f16* Q = QKV;
    f16* K = QKV + 4 * M1;
    f16* CTX = QKV + 8 * M1;       // alias Xb: x dead after QKV GEMM
    float* out = (float*)d_out;

    cast_all<<<dim3(8192), dim3(256), 0, stream>>>(x, wq, wk, wv, wo, Xb, Wh);
    gemm_qkv<<<dim3(32, 16), dim3(256), 0, stream>>>(Xb, Wh, Q, K, VT);
    attn<<<dim3(32, 32), dim3(256), 0, stream>>>(Q, K, VT, CTX);
    gemm_proj<<<dim3(64, 8), dim3(256), 0, stream>>>(CTX, Wh + 3 * M1, out, bo);
}

// Round 10
// 183.740 us; speedup vs baseline: 1.4598x; 1.0111x over previous
//
#include <hip/hip_runtime.h>

typedef _Float16 f16;
typedef _Float16 f16x2 __attribute__((ext_vector_type(2)));
typedef _Float16 f16x4 __attribute__((ext_vector_type(4)));
typedef _Float16 f16x8 __attribute__((ext_vector_type(8)));
typedef float f32x4 __attribute__((ext_vector_type(4)));
typedef int i32x4 __attribute__((ext_vector_type(4)));

#define MFMA(a, b, c) __builtin_amdgcn_mfma_f32_16x16x32_f16((a), (b), (c), 0, 0, 0)

typedef __attribute__((address_space(1))) const void gvoid;
typedef __attribute__((address_space(3))) void lvoid;

__device__ __forceinline__ void gload16(const void* g, void* l) {
    __builtin_amdgcn_global_load_lds((gvoid*)g, (lvoid*)l, 16, 0, 0);
}

// ---------------------------------------------------------------------------
// Kernel 1: cast f32 -> f16 for in_data (4M elems) and 4 weights (4x1M elems)
// ---------------------------------------------------------------------------
__global__ void cast_all(const float* __restrict__ x,
                         const float* __restrict__ w0, const float* __restrict__ w1,
                         const float* __restrict__ w2, const float* __restrict__ w3,
                         f16* __restrict__ xb, f16* __restrict__ wb) {
    const int NX = 4096 * 1024;
    int i = (blockIdx.x * 256 + threadIdx.x) * 4;
    if (i < NX) {
        float4 v = *(const float4*)(x + i);
        f16x4 o = {(f16)v.x, (f16)v.y, (f16)v.z, (f16)v.w};
        *(f16x4*)(xb + i) = o;
    } else {
        int j = i - NX;  // [0, 4M)
        const float* s = (j < (1 << 20)) ? w0 : (j < (2 << 20)) ? w1
                       : (j < (3 << 20)) ? w2 : w3;
        int loc = j & ((1 << 20) - 1);
        float4 v = *(const float4*)(s + loc);
        f16x4 o = {(f16)v.x, (f16)v.y, (f16)v.z, (f16)v.w};
        *(f16x4*)(wb + j) = o;
    }
}

// ---------------------------------------------------------------------------
// Kernel 2: FUSED QKV GEMM, BM=128 BN=64 BK=64. Grid (32, 48): y = z*16 + n
// -> 1536 blocks = 6/CU (24 KB LDS). Simple 2-barrier loop (m97 structure;
// 6 co-resident blocks hide the drain), XOR-swizzled LDS (zero bank
// conflicts). 4 waves, each 64x32 out (4x2 frags, 16 MFMA/kt).
// Epilogues: z=0 -> Q * 0.125*log2(e); z=1 -> K; z=2 -> V transposed into
// VT[b*1024+n][2048].
// ---------------------------------------------------------------------------
__global__ __launch_bounds__(256) void gemm_qkv(const f16* __restrict__ A,
                                                const f16* __restrict__ W,
                                                f16* __restrict__ Qo,
                                                f16* __restrict__ Ko,
                                                f16* __restrict__ VTo) {
    __shared__ __align__(16) f16 As[128 * 64];
    __shared__ __align__(16) f16 Bs[64 * 64];
    const int tid = threadIdx.x;
    const int lane = tid & 63, w = tid >> 6;
    const int lo = lane & 15, hi = lane >> 4;
    const int wr = w >> 1, wc = w & 1;
    const int m0 = blockIdx.x * 128;
    const int by = blockIdx.y;
    const int z = by >> 4;               // 0=Q, 1=K, 2=V
    const int n0 = (by & 15) * 64;
    const char* Ab = (const char*)A;
    const char* Wb = (const char*)W + (size_t)z * 2097152;

    f32x4 acc[4][2];
#pragma unroll
    for (int i = 0; i < 4; ++i) {
        acc[i][0] = (f32x4){0.f, 0.f, 0.f, 0.f};
        acc[i][1] = (f32x4){0.f, 0.f, 0.f, 0.f};
    }

    for (int kt = 0; kt < 16; ++kt) {
        const int kb = kt * 128;
#pragma unroll
        for (int rr = 0; rr < 4; ++rr) {  // A: 128 rows x 128 B
            int o = rr * 4096 + tid * 16;
            int row = o >> 7;
            int colB = (o & 127) ^ ((row & 7) << 4);
            gload16(Ab + (size_t)(m0 + row) * 2048 + kb + colB, (char*)As + o);
        }
#pragma unroll
        for (int rr = 0; rr < 2; ++rr) {  // B: 64 rows x 128 B
            int o = rr * 4096 + tid * 16;
            int row = o >> 7;
            int colB = (o & 127) ^ ((row & 7) << 4);
            gload16(Wb + (size_t)(n0 + row) * 2048 + kb + colB, (char*)Bs + o);
        }
        __syncthreads();
#pragma unroll
        for (int kc = 0; kc < 2; ++kc) {
            f16x8 af[4], bf[2];
#pragma unroll
            for (int f = 0; f < 4; ++f) {
                const int row = wr * 64 + f * 16 + lo;
                const int cb = (kc * 64 + hi * 16) ^ ((row & 7) << 4);
                af[f] = *(const f16x8*)((const char*)As + row * 128 + cb);
            }
#pragma unroll
            for (int f = 0; f < 2; ++f) {
                const int row = wc * 32 + f * 16 + lo;
                const int cb = (kc * 64 + hi * 16) ^ ((row & 7) << 4);
                bf[f] = *(const f16x8*)((const char*)Bs + row * 128 + cb);
            }
#pragma unroll
            for (int i = 0; i < 4; ++i)
#pragma unroll
                for (int j = 0; j < 2; ++j) acc[i][j] = MFMA(af[i], bf[j], acc[i][j]);
        }
        __syncthreads();
    }

    const int mb = m0 + wr * 64 + hi * 4;
    const int nb = n0 + wc * 32 + lo;
    if (z == 0) {
#pragma unroll
        for (int i = 0; i < 4; ++i)
#pragma unroll
            for (int j = 0; j < 2; ++j)
#pragma unroll
                for (int r = 0; r < 4; ++r)
                    Qo[(size_t)(mb + i * 16 + r) * 1024 + nb + j * 16] =
                        (f16)(acc[i][j][r] * 0.18033688f);
    } else if (z == 1) {
#pragma unroll
        for (int i = 0; i < 4; ++i)
#pragma unroll
            for (int j = 0; j < 2; ++j)
#pragma unroll
                for (int r = 0; r < 4; ++r)
                    Ko[(size_t)(mb + i * 16 + r) * 1024 + nb + j * 16] =
                        (f16)acc[i][j][r];
    } else {
        // V transposed: VT[(b*1024 + n)][s], m = b*2048+s
#pragma unroll
        for (int i = 0; i < 4; ++i)
#pragma unroll
            for (int j = 0; j < 2; ++j)
#pragma unroll
                for (int r = 0; r < 4; ++r) {
                    const int m = mb + i * 16 + r, n = nb + j * 16;
                    VTo[(size_t)((m >> 11) * 1024 + n) * 2048 + (m & 2047)] =
                        (f16)acc[i][j][r];
                }
    }
}

// ---------------------------------------------------------------------------
// Kernel 3: causal flash attention — 8-wave blocks (512 thr), QBLK=128.
// Same proven per-wave algorithm as r6 (swapped QK^T, exp2 softmax,
// defer-max, register-P PV -> ctx^T); KVBLK=64 staging now serves 8 waves
// (2x MFMA per barrier, half the staging traffic). Per-wave early exit
// t < nt_w keeps causal work identical; barriers uniform across block.
// Grid (32 bh, 16 qi), ALL 512 blocks co-resident (2/CU, 16 waves/CU).
// qt = qi<8 ? qi : 23-qi  => paired blocks (i, i+256) sum to 15 steps.
// ---------------------------------------------------------------------------
__global__ __launch_bounds__(512) void attn(const f16* __restrict__ Q,
                                            const f16* __restrict__ K,
                                            const f16* __restrict__ VT,
                                            f16* __restrict__ CTX) {
    __shared__ __align__(16) f16 K0[64 * 64];
    __shared__ __align__(16) f16 K1[64 * 64];
    __shared__ __align__(16) f16 V0[64 * 64];
    __shared__ __align__(16) f16 V1[64 * 64];
    const int tid = threadIdx.x;
    const int lane = tid & 63, w = tid >> 6;           // w = 0..7
    const int lo = lane & 15, hi = lane >> 4;
    const int bh = blockIdx.x;
    const int qi = blockIdx.y;
    const int qt = (qi < 8) ? qi : 23 - qi;            // load-balance pairing
    const int b = bh >> 4, h = bh & 15;
    const int qw0 = qt * 128 + w * 16;
    const int qglob = qw0 + lo;
    const int ntb = qt * 2 + 2;                        // block kv-steps
    const int nt_w = qt * 2 + 1 + (w >> 2);            // this wave's kv-steps

    const f16* qrow = Q + (size_t)(b * 2048 + qw0 + lo) * 1024 + h * 64 + hi * 8;
    const f16x8 qa0 = *(const f16x8*)(qrow);
    const f16x8 qa1 = *(const f16x8*)(qrow + 32);

    f32x4 ctx[4];
#pragma unroll
    for (int d = 0; d < 4; ++d) ctx[d] = (f32x4){0.f, 0.f, 0.f, 0.f};
    float mrun = -3e38f, lsum = 0.f;

    const int idx0 = (2 * (hi & 1)) * 16 + lo;   // j2 in {0,1}
    const int idx1 = idx0 + 16;                  // j2 in {2,3}

    const char* Kb = (const char*)K;
    const char* Vb = (const char*)VT;

    auto stage = [&](f16* Kd, f16* Vd, int t) {
        const int kv0 = t * 64;
        // 512 threads x 16 B = one pass per 8 KB tile
        int o = tid * 16;
        int row = o >> 7;
        int colB = (o & 127) ^ ((row & 7) << 4);
        gload16(Kb + (size_t)(b * 2048 + kv0 + row) * 2048 + h * 128 + colB,
                (char*)Kd + o);
        gload16(Vb + (size_t)(b * 1024 + h * 64 + row) * 4096 + (size_t)kv0 * 2 + colB,
                (char*)Vd + o);
    };

    auto compute = [&](const f16* Klb, const f16* Vlb, bool diag, int t) {
        f32x4 s4[4];
        __builtin_amdgcn_s_setprio(1);
#pragma unroll
        for (int fj = 0; fj < 4; ++fj) {
            f32x4 a = (f32x4){0.f, 0.f, 0.f, 0.f};
            const int kv = fj * 16 + lo;
#pragma unroll
            for (int kc = 0; kc < 2; ++kc) {
                const int cb = (kc * 64 + hi * 16) ^ ((kv & 7) << 4);
                f16x8 kf = *(const f16x8*)((const char*)Klb + kv * 128 + cb);
                a = MFMA(kf, kc ? qa1 : qa0, a);
            }
            s4[fj] = a;
        }
        __builtin_amdgcn_s_setprio(0);

        float pv[16];
        if (diag) {
#pragma unroll
            for (int fj = 0; fj < 4; ++fj)
#pragma unroll
                for (int r = 0; r < 4; ++r) {
                    const int kvg = t * 64 + fj * 16 + hi * 4 + r;
                    pv[fj * 4 + r] = (kvg > qglob) ? -1e38f : s4[fj][r];
                }
        } else {
#pragma unroll
            for (int fj = 0; fj < 4; ++fj)
#pragma unroll
                for (int r = 0; r < 4; ++r) pv[fj * 4 + r] = s4[fj][r];
        }

        float tm[8];
#pragma unroll
        for (int i = 0; i < 8; ++i) tm[i] = fmaxf(pv[i], pv[i + 8]);
#pragma unroll
        for (int i = 0; i < 4; ++i) tm[i] = fmaxf(tm[i], tm[i + 4]);
        const float mxl = fmaxf(fmaxf(tm[0], tm[1]), fmaxf(tm[2], tm[3]));

        if (__any(mxl > mrun + 8.0f)) {
            float mxg = fmaxf(mxl, __shfl_xor(mxl, 16));
            mxg = fmaxf(mxg, __shfl_xor(mxg, 32));
            const float mnew = fmaxf(mrun, mxg);
            const float corr = __builtin_amdgcn_exp2f(mrun - mnew);
            mrun = mnew;
            lsum *= corr;
#pragma unroll
            for (int d = 0; d < 4; ++d) {
                ctx[d][0] *= corr; ctx[d][1] *= corr;
                ctx[d][2] *= corr; ctx[d][3] *= corr;
            }
        }

#pragma unroll
        for (int i = 0; i < 16; ++i) pv[i] = __builtin_amdgcn_exp2f(pv[i] - mrun);
        float ts[8];
#pragma unroll
        for (int i = 0; i < 8; ++i) ts[i] = pv[i] + pv[i + 8];
#pragma unroll
        for (int i = 0; i < 4; ++i) ts[i] = ts[i] + ts[i + 4];
        lsum += (ts[0] + ts[1]) + (ts[2] + ts[3]);

        int ph[4][2];
#pragma unroll
        for (int fj = 0; fj < 4; ++fj)
#pragma unroll
            for (int r2 = 0; r2 < 2; ++r2) {
                f16x2 hpair = {(f16)pv[fj * 4 + 2 * r2], (f16)pv[fj * 4 + 2 * r2 + 1]};
                ph[fj][r2] = __builtin_bit_cast(int, hpair);
            }

        f16x8 pb[2];
#pragma unroll
        for (int kc = 0; kc < 2; ++kc) {
            i32x4 dw;
#pragma unroll
            for (int j2 = 0; j2 < 4; ++j2) {
                const int idx = (j2 < 2) ? idx0 : idx1;
                int vA = __shfl(ph[2 * kc][j2 & 1], idx);
                int vB = __shfl(ph[2 * kc + 1][j2 & 1], idx);
                dw[j2] = (hi & 2) ? vB : vA;
            }
            pb[kc] = __builtin_bit_cast(f16x8, dw);
        }

        __builtin_amdgcn_s_setprio(1);
#pragma unroll
        for (int df = 0; df < 4; ++df) {
            const int d = df * 16 + lo;
#pragma unroll
            for (int kc = 0; kc < 2; ++kc) {
                const int cb = (kc * 64 + hi * 16) ^ ((d & 7) << 4);
                f16x8 vf = *(const f16x8*)((const char*)Vlb + d * 128 + cb);
                ctx[df] = MFMA(vf, pb[kc], ctx[df]);
            }
        }
        __builtin_amdgcn_s_setprio(0);
    };

    stage(&K0[0], &V0[0], 0);
    for (int t = 0; t < ntb; ++t) {
        __syncthreads();  // drains stage(t) loads (all waves) + full fence
        if ((t & 1) == 0) {
            if (t + 1 < ntb) stage(&K1[0], &V1[0], t + 1);
            if (t < nt_w) compute(&K0[0], &V0[0], t == nt_w - 1, t);
        } else {
            if (t + 1 < ntb) stage(&K0[0], &V0[0], t + 1);
            if (t < nt_w) compute(&K1[0], &V1[0], t == nt_w - 1, t);
        }
    }

    float lt = lsum + __shfl_xor(lsum, 16);
    lt += __shfl_xor(lt, 32);
    const float inv = 1.0f / lt;
#pragma unroll
    for (int df = 0; df < 4; ++df) {
        f16x4 o = {(f16)(ctx[df][0] * inv), (f16)(ctx[df][1] * inv),
                   (f16)(ctx[df][2] * inv), (f16)(ctx[df][3] * inv)};
        *(f16x4*)(CTX + (size_t)(b * 2048 + qw0 + lo) * 1024 + h * 64 + df * 16 + hi * 4) = o;
    }
}

// ---------------------------------------------------------------------------
// Kernel 4: output projection, BM=64 BN=64 BK=64. Grid (64,16) = 1024 blocks
// = 4/CU (16 KB LDS). 2-barrier loop, swizzled. 4 waves, each 32x32 out.
// ---------------------------------------------------------------------------
__global__ __launch_bounds__(256) void gemm_proj(const f16* __restrict__ A,
                                                 const f16* __restrict__ Bw,
                                                 float* __restrict__ Co,
                                                 const float* __restrict__ bias) {
    __shared__ __align__(16) f16 As[64 * 64];
    __shared__ __align__(16) f16 Bs[64 * 64];
    const int tid = threadIdx.x;
    const int lane = tid & 63, w = tid >> 6;
    const int lo = lane & 15, hi = lane >> 4;
    const int wr = w >> 1, wc = w & 1;
    const int m0 = blockIdx.x * 64, n0 = blockIdx.y * 64;
    const char* Ab = (const char*)A;
    const char* Bb = (const char*)Bw;

    f32x4 acc[2][2];
    acc[0][0] = acc[0][1] = acc[1][0] = acc[1][1] = (f32x4){0.f, 0.f, 0.f, 0.f};

    for (int kt = 0; kt < 16; ++kt) {
        const int kb = kt * 128;
#pragma unroll
        for (int rr = 0; rr < 2; ++rr) {  // A: 64 rows x 128 B
            int o = rr * 4096 + tid * 16;
            int row = o >> 7;
            int colB = (o & 127) ^ ((row & 7) << 4);
            gload16(Ab + (size_t)(m0 + row) * 2048 + kb + colB, (char*)As + o);
        }
#pragma unroll
        for (int rr = 0; rr < 2; ++rr) {  // B: 64 rows x 128 B
            int o = rr * 4096 + tid * 16;
            int row = o >> 7;
            int colB = (o & 127) ^ ((row & 7) << 4);
            gload16(Bb + (size_t)(n0 + row) * 2048 + kb + colB, (char*)Bs + o);
        }
        __syncthreads();
#pragma unroll
        for (int kc = 0; kc < 2; ++kc) {
            f16x8 af[2], bf[2];
#pragma unroll
            for (int f = 0; f < 2; ++f) {
                const int row = wr * 32 + f * 16 + lo;
                const int cb = (kc * 64 + hi * 16) ^ ((row & 7) << 4);
                af[f] = *(const f16x8*)((const char*)As + row * 128 + cb);
            }
#pragma unroll
            for (int f = 0; f < 2; ++f) {
                const int row = wc * 32 + f * 16 + lo;
                const int cb = (kc * 64 + hi * 16) ^ ((row & 7) << 4);
                bf[f] = *(const f16x8*)((const char*)Bs + row * 128 + cb);
            }
#pragma unroll
            for (int i = 0; i < 2; ++i)
#pragma unroll
                for (int j = 0; j < 2; ++j) acc[i][j] = MFMA(af[i], bf[j], acc[i][j]);
        }
        __syncthreads();
    }

    const int mb = m0 + wr * 32 + hi * 4;
    const int nb = n0 + wc * 32 + lo;
#pragma unroll
    for (int j = 0; j < 2; ++j) {
        float bj = bias[nb + j * 16];
#pragma unroll
        for (int i = 0; i < 2; ++i)
#pragma unroll
            for (int r = 0; r < 4; ++r)
                Co[(size_t)(mb + i * 16 + r) * 1024 + nb + j * 16] =
                    acc[i][j][r] + bj;
    }
}

// ---------------------------------------------------------------------------
extern "C" void kernel_launch(void* const* d_in, const int* in_sizes, int n_in,
                              void* d_out, int out_size, void* d_ws, size_t ws_size,
                              hipStream_t stream) {
    const float* x = (const float*)d_in[0];
    const float* wq = (const float*)d_in[1];
    const float* wk = (const float*)d_in[2];
    const float* wv = (const float*)d_in[3];
    const float* wo = (const float*)d_in[4];
    const float* bo = (const float*)d_in[5];

    const size_t M1 = 1024 * 1024;
    f16* VT = (f16*)d_ws;          // 4M f16 (8 MB): V transposed [b*1024+n][2048]
    f16* Wh = VT + 4 * M1;         // 4M f16: Wq|Wk|Wv|Wo
    f16* QKV = Wh + 4 * M1;        // Q (4M) | K (4M)
    f16* Xb = QKV + 8 * M1;        // x cast; region later reused as CTX
    f16* Q = QKV;
    f16* K = QKV + 4 * M1;
    f16* CTX = QKV + 8 * M1;       // alias Xb: x dead after QKV GEMM
    float* out = (float*)d_out;

    cast_all<<<dim3(8192), dim3(256), 0, stream>>>(x, wq, wk, wv, wo, Xb, Wh);
    gemm_qkv<<<dim3(32, 48), dim3(256), 0, stream>>>(Xb, Wh, Q, K, VT);
    attn<<<dim3(32, 16), dim3(512), 0, stream>>>(Q, K, VT, CTX);
    gemm_proj<<<dim3(64, 16), dim3(256), 0, stream>>>(CTX, Wh + 3 * M1, out, bo);
}